// Round 21
// baseline (137.095 us; speedup 1.0000x reference)
//
#include <hip/hip_runtime.h>

constexpr int G = 64;
constexpr int C = 16;
constexpr int NBATCH = 4;
constexpr int HID = 96;
constexpr int G3 = G * G * G; // 262144 = 2^18

typedef _Float16 h2    __attribute__((ext_vector_type(2)));
typedef _Float16 f16x4 __attribute__((ext_vector_type(4)));
typedef _Float16 f16x8 __attribute__((ext_vector_type(8)));
typedef float    f32x4 __attribute__((ext_vector_type(4)));
typedef float    f32x2 __attribute__((ext_vector_type(2)));

__device__ __forceinline__ f32x4 mfma16(f16x8 a, f16x8 b, f32x4 c) {
    return __builtin_amdgcn_mfma_f32_16x16x32_f16(a, b, c, 0, 0, 0);
}
__device__ __forceinline__ f32x2 pk_fma(f32x2 a, f32x2 b, f32x2 c) {
    return __builtin_elementwise_fma(a, b, c); // -> v_pk_fma_f32
}
__device__ __forceinline__ f32x2 pk_max(f32x2 a, f32x2 b) {
    return __builtin_elementwise_max(a, b);    // -> v_pk_max_f32
}

#if __has_builtin(__builtin_amdgcn_global_load_lds)
#define HAS_GLL 1
__device__ __forceinline__ void gload_lds(const float* g, float* l) {
    __builtin_amdgcn_global_load_lds(
        (const __attribute__((address_space(1))) void*)g,
        (__attribute__((address_space(3))) void*)l, 4, 0, 0);
}
#else
#define HAS_GLL 0
#endif

// ---------------------------------------------------------------------------
// Pass 0: pack W1 (96x64) and W2 (16x96) into MFMA A-fragment order (f16).
// A-frag for mfma_f32_16x16x32_f16: lane l holds A[row = l%16][k = (l/16)*8+j],
// j=0..7 (16B contiguous per lane). (Layout verified by R11: absmax 0.03125.)
// ---------------------------------------------------------------------------
__global__ __launch_bounds__(256)
void nca_packw(const float* __restrict__ w1, const float* __restrict__ w2,
               _Float16* __restrict__ a1p, _Float16* __restrict__ a2p)
{
    const int i = blockIdx.x * 256 + threadIdx.x; // 0..6143
    {
        const int j = i & 7, lane = (i >> 3) & 63, f = i >> 9; // f = mt*2+kt
        const int mt = f >> 1, kt = f & 1;
        const int y = mt * 16 + (lane & 15);
        const int x = kt * 32 + ((lane >> 4) << 3) + j;
        a1p[i] = (_Float16)w1[y * 64 + x];
    }
    if (i < 3 * 512) {
        const int j = i & 7, lane = (i >> 3) & 63, kt2 = i >> 9;
        const int c = lane & 15;
        const int y = kt2 * 32 + ((lane >> 4) << 3) + j;
        a2p[i] = (_Float16)w2[c * HID + y];
    }
}

// ---------------------------------------------------------------------------
// Pass 1: perception + MFMA MLP + pre-alive fold-in.
//
// R21 = R20 + packed-f32 stencil (channel pairs via v_pk_*_f32).
// R20's counters: VALU 44.6% is the top pipe (LDS conflicts only ~18% of
// cycles -- the R20 swizzle theory was mostly wrong); occupancy is capped
// at 12 waves/CU by the proven-necessary 84 VGPR. The stencil's 16
// channels are independent -> process pairs (2p, 2p+1) as float2: clang
// emits full-rate VOP3P v_pk_fma_f32/v_pk_add_f32/v_pk_max_f32 on CDNA,
// halving stencil VALU issue (worst case half-rate pk = issue-neutral).
// Per-channel f32 arithmetic class unchanged. Channel pairs align exactly
// with pp[j]'s (2j, 2j+1) f16 packing -> pf-carry machinery deleted.
// Everything else R20-verbatim (padded SY=12/SZ=120 halo, X swizzle,
// voxel-major epilogue, lazy post-mask).
// Invariant: WRITE_SIZE 69632 KB (zero spill).
// ---------------------------------------------------------------------------
constexpr int SYp = 12;             // padded row stride (floats)
constexpr int SZp = 120;            // padded plane stride (floats)
constexpr int SLOTS = 6 * SZp;      // 720 slots per channel (6 z-planes)
constexpr int BUF_F = 8 * SLOTS;    // 5760 floats per 8-channel buffer
constexpr int XROW = 128;           // X-panel row stride (bytes), swizzled
constexpr int XWAVE = 64 * XROW;    // 8192 B per wave
constexpr int HROW = 80;            // H / delta-transpose row stride (bytes)

__global__ __launch_bounds__(256, 3)
void nca_update(const float* __restrict__ state, const float* __restrict__ rand_u,
                const _Float16* __restrict__ a1p, const float* __restrict__ b1,
                const _Float16* __restrict__ a2p,
                float* __restrict__ out, float* __restrict__ acopy)
{
    // Stencil: 2 x 5760 floats = 46080 B. GEMM panels (4 x 8192 = 32768 B)
    // alias the same region after the post-stencil barrier.
    __shared__ __align__(16) char smem[2 * BUF_F * 4];
    float* buf0 = (float*)smem;
    float* buf1 = buf0 + BUF_F;

    const int tid = threadIdx.x;
    const int bid = blockIdx.x;
    const int bx = bid & 7, by = (bid >> 3) & 7, bz = (bid >> 6) & 15, n = bid >> 10;
    const int x0 = bx * 8, y0 = by * 8, z0 = bz * 4;
    const float* sb = state + (size_t)n * C * G3;

    // --- halo source offsets for padded slots (identical every channel).
    //     Slot s: lz = s/120, ly = (s%120)/12, lx = (s%120)%12.
    //     lx>=10 is a pad slot: load a clamped dummy (never read).
    int vo0, vo1, vo2;
    {
        const int j = tid;
        const int lz = j / SZp, rr = j % SZp, ly = rr / SYp, lx = min(rr % SYp, 9);
        vo0 = min(max(z0 + lz - 1, 0), G - 1) * (G * G)
            + min(max(y0 + ly - 1, 0), G - 1) * G
            + min(max(x0 + lx - 1, 0), G - 1);
    }
    {
        const int j = tid + 256;
        const int lz = j / SZp, rr = j % SZp, ly = rr / SYp, lx = min(rr % SYp, 9);
        vo1 = min(max(z0 + lz - 1, 0), G - 1) * (G * G)
            + min(max(y0 + ly - 1, 0), G - 1) * G
            + min(max(x0 + lx - 1, 0), G - 1);
    }
    const bool act2 = (tid + 512 < SLOTS); // tid < 208
    {
        const int j = min(tid + 512, SLOTS - 1);
        const int lz = j / SZp, rr = j % SZp, ly = rr / SYp, lx = min(rr % SYp, 9);
        vo2 = min(max(z0 + lz - 1, 0), G - 1) * (G * G)
            + min(max(y0 + ly - 1, 0), G - 1) * G
            + min(max(x0 + lx - 1, 0), G - 1);
    }
    const int wbase = tid & ~63; // wave-uniform LDS slot base

    // Own voxel (== lane's voxel of wave's z-slice).
    const int lxl = (tid & 7) + 1, lyl = ((tid >> 3) & 7) + 1, lzl = (tid >> 6) + 1;
    const int cbase = (lzl - 1) * SZp + (lyl - 1) * SYp + (lxl - 1);
    const size_t vofs = (size_t)(z0 + lzl - 1) * (G * G)
                      + (size_t)(y0 + lyl - 1) * G + (x0 + lxl - 1);
    const float ru = rand_u[(size_t)n * G3 + vofs]; // own rand, issued early

#if HAS_GLL
    // --- issue group 0 (ch 0-7) -> buf0, async, zero VGPR ---
#pragma unroll
    for (int c = 0; c < 8; ++c) {
        const float* gc = sb + (size_t)c * G3;
        gload_lds(gc + vo0, buf0 + c * SLOTS + wbase);
        gload_lds(gc + vo1, buf0 + c * SLOTS + 256 + wbase);
        if (act2) gload_lds(gc + vo2, buf0 + c * SLOTS + 512 + wbase);
    }
    __syncthreads(); // drains vmcnt -> buf0 complete

    // --- issue group 1 (ch 8-15) -> buf1; latency hides under stencil g0 ---
#pragma unroll
    for (int c = 0; c < 8; ++c) {
        const float* gc = sb + (size_t)(8 + c) * G3;
        gload_lds(gc + vo0, buf1 + c * SLOTS + wbase);
        gload_lds(gc + vo1, buf1 + c * SLOTS + 256 + wbase);
        if (act2) gload_lds(gc + vo2, buf1 + c * SLOTS + 512 + wbase);
    }
#else
    // Fallback: synchronous staging (correct, no overlap).
#pragma unroll
    for (int c = 0; c < 8; ++c) {
        const float* gc = sb + (size_t)c * G3;
        buf0[c * SLOTS + tid] = gc[vo0];
        buf0[c * SLOTS + 256 + tid] = gc[vo1];
        if (act2) buf0[c * SLOTS + 512 + tid] = gc[vo2];
    }
    __syncthreads();
#pragma unroll
    for (int c = 0; c < 8; ++c) {
        const float* gc = sb + (size_t)(8 + c) * G3;
        buf1[c * SLOTS + tid] = gc[vo0];
        buf1[c * SLOTS + 256 + tid] = gc[vo1];
        if (act2) buf1[c * SLOTS + 512 + tid] = gc[vo2];
    }
#endif

    // Packed perception features + exact fp32 centers.
    h2 pp[32];
    float ctrf[C]; // own-voxel centers: exact s0 passthrough
    float amax = -3.0e38f;

#pragma unroll
    for (int g = 0; g < 2; ++g) {
        const float* bb = g ? buf1 : buf0;
        if (g) __syncthreads(); // drains buf1's loads (issued pre-stencil-g0)

#pragma unroll
        for (int p = 0; p < 4; ++p) {           // channel pair (cg, cg+1)
            const int cg = g * 8 + 2 * p;
            const float* bA = bb + (2 * p) * SLOTS;
            const float* bB = bA + SLOTS;
            f32x2 P0 = {0.f, 0.f}, P2 = {0.f, 0.f};
            f32x2 U0 = {0.f, 0.f}, U2 = {0.f, 0.f};
            f32x2 V0 = {0.f, 0.f}, V2 = {0.f, 0.f};
            f32x2 ctr2 = {0.f, 0.f};
            f32x2 mx2 = {-3.0e38f, -3.0e38f};
#pragma unroll
            for (int dz = 0; dz < 3; ++dz) {
                const float gzw = (dz == 1) ? 2.f : 1.f;
#pragma unroll
                for (int dy = 0; dy < 3; ++dy) {
                    const float gyw = (dy == 1) ? 2.f : 1.f;
                    const int off = cbase + dz * SZp + dy * SYp;
                    f32x2 a0, a1, a2;
                    a0.x = bA[off];     a0.y = bB[off];
                    a1.x = bA[off + 1]; a1.y = bB[off + 1];
                    a2.x = bA[off + 2]; a2.y = bB[off + 2];
                    const f32x2 two = {2.f, 2.f};
                    const f32x2 rs = a0 + two * a1 + a2; // v_pk contract
                    const f32x2 gy2 = {gyw, gyw};
                    const f32x2 gz2 = {gzw, gzw};
                    const f32x2 gw2 = {gzw * gyw, gzw * gyw};
                    if (dz == 0) P0 = pk_fma(gy2, rs, P0);
                    if (dz == 2) P2 = pk_fma(gy2, rs, P2);
                    if (dy == 0) U0 = pk_fma(gz2, rs, U0);
                    if (dy == 2) U2 = pk_fma(gz2, rs, U2);
                    V0 = pk_fma(gw2, a0, V0);
                    V2 = pk_fma(gw2, a2, V2);
                    if (dz == 1 && dy == 1) ctr2 = a1;
                    if (cg == 2) mx2 = pk_max(mx2, pk_max(pk_max(a0, a1), a2));
                }
            }
            if (cg == 2) amax = mx2.y; // alpha = channel 3 = .y of pair (2,3)
            ctrf[cg]     = ctr2.x;
            ctrf[cg + 1] = ctr2.y;

            const f32x2 sc = {0.0625f, 0.0625f};
            const f32x2 f1 = (P0 - P2) * sc;
            const f32x2 f2 = (U0 - U2) * sc;
            const f32x2 f3 = (V0 - V2) * sc;

            const int j = g * 4 + p; // == cg >> 1
            h2 v;
            v.x = (_Float16)ctr2.x; v.y = (_Float16)ctr2.y; pp[j]      = v;
            v.x = (_Float16)f1.x;   v.y = (_Float16)f1.y;   pp[8 + j]  = v;
            v.x = (_Float16)f2.x;   v.y = (_Float16)f2.y;   pp[16 + j] = v;
            v.x = (_Float16)f3.x;   v.y = (_Float16)f3.y;   pp[24 + j] = v;
        }
    }

    // All waves finished reading the buffers; X/H panels may overwrite.
    __syncthreads();

    const float pre = (amax > 0.1f) ? 1.f : 0.f; // own voxel

    // =================== MFMA MLP (wave-private) ===================
    const int lane = tid & 63;
    const int w    = tid >> 6;       // wave = z-slice
    const int l15  = lane & 15;
    const int lg   = lane >> 4;      // lane group 0..3
    char* xw = smem + w * XWAVE;

    // --- write X-panel: row v = lane, 64 f16, XOR-swizzled 16B slots ---
#pragma unroll
    for (int q = 0; q < 8; ++q) {
        uint4 t;
        t.x = __builtin_bit_cast(unsigned, pp[4 * q]);
        t.y = __builtin_bit_cast(unsigned, pp[4 * q + 1]);
        t.z = __builtin_bit_cast(unsigned, pp[4 * q + 2]);
        t.w = __builtin_bit_cast(unsigned, pp[4 * q + 3]);
        *(uint4*)(xw + lane * XROW + ((q * 16) ^ ((lane & 7) << 4))) = t;
    }

    // --- load B1 fragments (X^T): B[k][v], lane: k=lg*8+j, v=nt*16+l15 ---
    f16x8 bfr[8]; // [kt*4 + nt]
#pragma unroll
    for (int kt = 0; kt < 2; ++kt)
#pragma unroll
        for (int nt = 0; nt < 4; ++nt) {
            const int v = nt * 16 + l15;
            bfr[kt * 4 + nt] = *(const f16x8*)(
                xw + v * XROW + ((kt * 64 + lg * 16) ^ ((v & 7) << 4)));
        }

    const f16x8* a1 = ((const f16x8*)a1p) + lane;
    const f16x8* a2 = ((const f16x8*)a2p) + lane;

    f32x4 acc2[4];
#pragma unroll
    for (int nt = 0; nt < 4; ++nt) acc2[nt] = (f32x4){0.f, 0.f, 0.f, 0.f};

    // --- interleaved GEMM1/GEMM2 per 32-row hidden block ---
    // (DS ops are per-wave in-order: H writes over the dead X region are
    //  safe after the bfr reads above.)
#pragma unroll 1
    for (int kt2 = 0; kt2 < 3; ++kt2) {
#pragma unroll
        for (int mtsub = 0; mtsub < 2; ++mtsub) {
            const int mt = kt2 * 2 + mtsub;
            const f16x8 a_0 = a1[(mt * 2 + 0) * 64];
            const f16x8 a_1 = a1[(mt * 2 + 1) * 64];
            const f32x4 bias = *(const f32x4*)(b1 + mt * 16 + lg * 4);
#pragma unroll
            for (int nt = 0; nt < 4; ++nt) {
                f32x4 acc = (f32x4){0.f, 0.f, 0.f, 0.f};
                acc = mfma16(a_0, bfr[nt],     acc);
                acc = mfma16(a_1, bfr[4 + nt], acc);
                f16x4 hv;
                hv[0] = (_Float16)fmaxf(acc[0] + bias[0], 0.f);
                hv[1] = (_Float16)fmaxf(acc[1] + bias[1], 0.f);
                hv[2] = (_Float16)fmaxf(acc[2] + bias[2], 0.f);
                hv[3] = (_Float16)fmaxf(acc[3] + bias[3], 0.f);
                *(f16x4*)(xw + (nt * 16 + l15) * HROW + mtsub * 32 + lg * 8) = hv;
            }
        }
        const f16x8 a2f = a2[kt2 * 64];
#pragma unroll
        for (int nt = 0; nt < 4; ++nt) {
            const f16x8 b2 = *(const f16x8*)(xw + (nt * 16 + l15) * HROW + lg * 16);
            acc2[nt] = mfma16(a2f, b2, acc2[nt]);
        }
    }

    // --- delta transpose through the (now dead) H panel: row = voxel ---
#pragma unroll
    for (int nt = 0; nt < 4; ++nt) {
        *(f32x4*)(xw + (nt * 16 + l15) * HROW + lg * 16) = acc2[nt];
    }

    // --- epilogue: own voxel, all 16 channels; s0 = ctrf (exact fp32) ---
    const float m = (ru < 0.5f) ? 1.f : 0.f;
    float* ob = out + (size_t)n * C * G3;
    float* ac = acopy + (size_t)n * G3;
#pragma unroll
    for (int q = 0; q < 4; ++q) {
        const f32x4 dv = *(const f32x4*)(xw + lane * HROW + q * 16);
#pragma unroll
        for (int r = 0; r < 4; ++r) {
            const int c = q * 4 + r;
            const float nv = fmaf(dv[r], m, ctrf[c]);
            if (c == 3) ac[vofs] = nv; // UNMASKED new alpha
            ob[(size_t)c * G3 + vofs] = nv * pre;
        }
    }
}

// ---------------------------------------------------------------------------
// Pass 2 (fused): post-alive pooling on the unmasked new alpha (acopy) ->
// zero out dead voxels only. Alive voxels (overwhelming majority) touch no
// out traffic: multiplying by 1 is a no-op. Bit-exact vs out *= mask.
// ---------------------------------------------------------------------------
__global__ __launch_bounds__(256)
void nca_post(const float* __restrict__ acopy, float* __restrict__ out)
{
    const int idx = blockIdx.x * 256 + threadIdx.x; // over NBATCH*G3
    const int n = idx >> 18;
    const int v = idx & (G3 - 1);
    const int x = v & 63, y = (v >> 6) & 63, z = v >> 12;
    const float* ab = acopy + (size_t)n * G3;
    float mx = -3.0e38f;
#pragma unroll
    for (int dz = -1; dz <= 1; ++dz) {
        const int zz = min(max(z + dz, 0), G - 1);
#pragma unroll
        for (int dy = -1; dy <= 1; ++dy) {
            const int yy = min(max(y + dy, 0), G - 1);
            const int xm = max(x - 1, 0), xp = min(x + 1, G - 1);
            const float* row = ab + (size_t)zz * (G * G) + (size_t)yy * G;
            mx = fmaxf(mx, fmaxf(fmaxf(row[xm], row[x]), row[xp]));
        }
    }
    if (mx > 0.1f) return; // alive: out already holds new_state * pre
    float* ob = out + (size_t)n * C * G3 + v;
#pragma unroll
    for (int c = 0; c < C; ++c) ob[(size_t)c * G3] = 0.f;
}

extern "C" void kernel_launch(void* const* d_in, const int* in_sizes, int n_in,
                              void* d_out, int out_size, void* d_ws, size_t ws_size,
                              hipStream_t stream)
{
    const float* state  = (const float*)d_in[0];
    const float* rand_u = (const float*)d_in[1];
    const float* w1     = (const float*)d_in[2];
    const float* b1     = (const float*)d_in[3];
    const float* w2     = (const float*)d_in[4];
    float* out  = (float*)d_out;

    // Workspace: [0,12KB) a1p, [12KB,15KB) a2p, [16KB, 16KB+4MiB) acopy.
    _Float16* a1p  = (_Float16*)d_ws;
    _Float16* a2p  = (_Float16*)((char*)d_ws + 12 * 1024);
    float*    acop = (float*)((char*)d_ws + 16 * 1024);

    nca_packw <<<24, 256, 0, stream>>>(w1, w2, a1p, a2p);
    nca_update<<<NBATCH * 8 * 8 * 16, 256, 0, stream>>>(state, rand_u, a1p, b1, a2p, out, acop);
    nca_post  <<<(NBATCH * G3) / 256, 256, 0, stream>>>(acop, out);
}

// Round 22
// 118.128 us; speedup vs baseline: 1.1606x; 1.1606x over previous
//
#include <hip/hip_runtime.h>

constexpr int G = 64;
constexpr int C = 16;
constexpr int NBATCH = 4;
constexpr int HID = 96;
constexpr int G3 = G * G * G; // 262144 = 2^18

typedef _Float16 h2    __attribute__((ext_vector_type(2)));
typedef _Float16 f16x4 __attribute__((ext_vector_type(4)));
typedef _Float16 f16x8 __attribute__((ext_vector_type(8)));
typedef float    f32x4 __attribute__((ext_vector_type(4)));
typedef float    f32x2 __attribute__((ext_vector_type(2)));

__device__ __forceinline__ f32x4 mfma16(f16x8 a, f16x8 b, f32x4 c) {
    return __builtin_amdgcn_mfma_f32_16x16x32_f16(a, b, c, 0, 0, 0);
}
__device__ __forceinline__ f32x2 pk_fma(f32x2 a, f32x2 b, f32x2 c) {
    return __builtin_elementwise_fma(a, b, c); // -> v_pk_fma_f32
}
__device__ __forceinline__ f32x2 pk_max(f32x2 a, f32x2 b) {
    return __builtin_elementwise_max(a, b);    // -> v_pk_max_f32
}

#if __has_builtin(__builtin_amdgcn_global_load_lds)
#define HAS_GLL 1
__device__ __forceinline__ void gload_lds(const float* g, float* l) {
    __builtin_amdgcn_global_load_lds(
        (const __attribute__((address_space(1))) void*)g,
        (__attribute__((address_space(3))) void*)l, 4, 0, 0);
}
#else
#define HAS_GLL 0
#endif

// ---------------------------------------------------------------------------
// Pass 0: pack W1 (96x64) and W2 (16x96) into MFMA A-fragment order (f16).
// A-frag for mfma_f32_16x16x32_f16: lane l holds A[row = l%16][k = (l/16)*8+j],
// j=0..7 (16B contiguous per lane). (Layout verified by R11: absmax 0.03125.)
// ---------------------------------------------------------------------------
__global__ __launch_bounds__(256)
void nca_packw(const float* __restrict__ w1, const float* __restrict__ w2,
               _Float16* __restrict__ a1p, _Float16* __restrict__ a2p)
{
    const int i = blockIdx.x * 256 + threadIdx.x; // 0..6143
    {
        const int j = i & 7, lane = (i >> 3) & 63, f = i >> 9; // f = mt*2+kt
        const int mt = f >> 1, kt = f & 1;
        const int y = mt * 16 + (lane & 15);
        const int x = kt * 32 + ((lane >> 4) << 3) + j;
        a1p[i] = (_Float16)w1[y * 64 + x];
    }
    if (i < 3 * 512) {
        const int j = i & 7, lane = (i >> 3) & 63, kt2 = i >> 9;
        const int c = lane & 15;
        const int y = kt2 * 32 + ((lane >> 4) << 3) + j;
        a2p[i] = (_Float16)w2[c * HID + y];
    }
}

// ---------------------------------------------------------------------------
// Pass 1: perception + MFMA MLP + pre-alive fold-in.
//
// R22 = R21 (pk-f32 stencil, validated: VALUBusy 44.6->31.3%) with the
// register bill paid: R21 spilled ~10.5 floats/thread at the (256,3) cap
// (live ~95 vs 85). Ledger fix:
//  - drop ctrf[16] (-16): s0 comes from the f16 identity features
//    (numerics validated R17/R18, absmax 0.03125 unchanged);
//  - avoid R18's mistake (+8 for keeping pp[0..7] live through the GEMM)
//    via R19's proven LDS parking: after the bfr reads, park pp[0..7] in
//    the X-panel dead zone (bytes 6144..8192/wave; H/transpose < 5120;
//    per-wave DS ordering makes write-after-read safe), read back in the
//    epilogue. Net demand ~= 79 < 85.
// Everything else R20/R21-verbatim (padded SY=12/SZ=120 halo, X swizzle,
// async 2-group staging, voxel-major epilogue, lazy post-mask).
// Invariant: WRITE_SIZE 69632 KB. Fifth spill => declare R16/R20 floor.
// ---------------------------------------------------------------------------
constexpr int SYp = 12;             // padded row stride (floats)
constexpr int SZp = 120;            // padded plane stride (floats)
constexpr int SLOTS = 6 * SZp;      // 720 slots per channel (6 z-planes)
constexpr int BUF_F = 8 * SLOTS;    // 5760 floats per 8-channel buffer
constexpr int XROW = 128;           // X-panel row stride (bytes), swizzled
constexpr int XWAVE = 64 * XROW;    // 8192 B per wave
constexpr int HROW = 80;            // H / delta-transpose row stride (bytes)
constexpr int PARK0 = 6144;        // identity parking (per wave), 1 KiB
constexpr int PARK1 = 7168;        // second KiB (ends at 8192)

__global__ __launch_bounds__(256, 3)
void nca_update(const float* __restrict__ state, const float* __restrict__ rand_u,
                const _Float16* __restrict__ a1p, const float* __restrict__ b1,
                const _Float16* __restrict__ a2p,
                float* __restrict__ out, float* __restrict__ acopy)
{
    // Stencil: 2 x 5760 floats = 46080 B. GEMM panels (4 x 8192 = 32768 B)
    // alias the same region after the post-stencil barrier.
    __shared__ __align__(16) char smem[2 * BUF_F * 4];
    float* buf0 = (float*)smem;
    float* buf1 = buf0 + BUF_F;

    const int tid = threadIdx.x;
    const int bid = blockIdx.x;
    const int bx = bid & 7, by = (bid >> 3) & 7, bz = (bid >> 6) & 15, n = bid >> 10;
    const int x0 = bx * 8, y0 = by * 8, z0 = bz * 4;
    const float* sb = state + (size_t)n * C * G3;

    // --- halo source offsets for padded slots (identical every channel).
    //     Slot s: lz = s/120, ly = (s%120)/12, lx = (s%120)%12.
    //     lx>=10 is a pad slot: load a clamped dummy (never read).
    int vo0, vo1, vo2;
    {
        const int j = tid;
        const int lz = j / SZp, rr = j % SZp, ly = rr / SYp, lx = min(rr % SYp, 9);
        vo0 = min(max(z0 + lz - 1, 0), G - 1) * (G * G)
            + min(max(y0 + ly - 1, 0), G - 1) * G
            + min(max(x0 + lx - 1, 0), G - 1);
    }
    {
        const int j = tid + 256;
        const int lz = j / SZp, rr = j % SZp, ly = rr / SYp, lx = min(rr % SYp, 9);
        vo1 = min(max(z0 + lz - 1, 0), G - 1) * (G * G)
            + min(max(y0 + ly - 1, 0), G - 1) * G
            + min(max(x0 + lx - 1, 0), G - 1);
    }
    const bool act2 = (tid + 512 < SLOTS); // tid < 208
    {
        const int j = min(tid + 512, SLOTS - 1);
        const int lz = j / SZp, rr = j % SZp, ly = rr / SYp, lx = min(rr % SYp, 9);
        vo2 = min(max(z0 + lz - 1, 0), G - 1) * (G * G)
            + min(max(y0 + ly - 1, 0), G - 1) * G
            + min(max(x0 + lx - 1, 0), G - 1);
    }
    const int wbase = tid & ~63; // wave-uniform LDS slot base

    // Own voxel (== lane's voxel of wave's z-slice).
    const int lxl = (tid & 7) + 1, lyl = ((tid >> 3) & 7) + 1, lzl = (tid >> 6) + 1;
    const int cbase = (lzl - 1) * SZp + (lyl - 1) * SYp + (lxl - 1);
    const size_t vofs = (size_t)(z0 + lzl - 1) * (G * G)
                      + (size_t)(y0 + lyl - 1) * G + (x0 + lxl - 1);
    const float ru = rand_u[(size_t)n * G3 + vofs]; // own rand, issued early

#if HAS_GLL
    // --- issue group 0 (ch 0-7) -> buf0, async, zero VGPR ---
#pragma unroll
    for (int c = 0; c < 8; ++c) {
        const float* gc = sb + (size_t)c * G3;
        gload_lds(gc + vo0, buf0 + c * SLOTS + wbase);
        gload_lds(gc + vo1, buf0 + c * SLOTS + 256 + wbase);
        if (act2) gload_lds(gc + vo2, buf0 + c * SLOTS + 512 + wbase);
    }
    __syncthreads(); // drains vmcnt -> buf0 complete

    // --- issue group 1 (ch 8-15) -> buf1; latency hides under stencil g0 ---
#pragma unroll
    for (int c = 0; c < 8; ++c) {
        const float* gc = sb + (size_t)(8 + c) * G3;
        gload_lds(gc + vo0, buf1 + c * SLOTS + wbase);
        gload_lds(gc + vo1, buf1 + c * SLOTS + 256 + wbase);
        if (act2) gload_lds(gc + vo2, buf1 + c * SLOTS + 512 + wbase);
    }
#else
    // Fallback: synchronous staging (correct, no overlap).
#pragma unroll
    for (int c = 0; c < 8; ++c) {
        const float* gc = sb + (size_t)c * G3;
        buf0[c * SLOTS + tid] = gc[vo0];
        buf0[c * SLOTS + 256 + tid] = gc[vo1];
        if (act2) buf0[c * SLOTS + 512 + tid] = gc[vo2];
    }
    __syncthreads();
#pragma unroll
    for (int c = 0; c < 8; ++c) {
        const float* gc = sb + (size_t)(8 + c) * G3;
        buf1[c * SLOTS + tid] = gc[vo0];
        buf1[c * SLOTS + 256 + tid] = gc[vo1];
        if (act2) buf1[c * SLOTS + 512 + tid] = gc[vo2];
    }
#endif

    // Packed perception features (pairs; pp[0..7] = identity = f16 s0).
    h2 pp[32];
    float amax = -3.0e38f;

#pragma unroll
    for (int g = 0; g < 2; ++g) {
        const float* bb = g ? buf1 : buf0;
        if (g) __syncthreads(); // drains buf1's loads (issued pre-stencil-g0)

#pragma unroll
        for (int p = 0; p < 4; ++p) {           // channel pair (cg, cg+1)
            const int cg = g * 8 + 2 * p;
            const float* bA = bb + (2 * p) * SLOTS;
            const float* bB = bA + SLOTS;
            f32x2 P0 = {0.f, 0.f}, P2 = {0.f, 0.f};
            f32x2 U0 = {0.f, 0.f}, U2 = {0.f, 0.f};
            f32x2 V0 = {0.f, 0.f}, V2 = {0.f, 0.f};
            f32x2 ctr2 = {0.f, 0.f};
            f32x2 mx2 = {-3.0e38f, -3.0e38f};
#pragma unroll
            for (int dz = 0; dz < 3; ++dz) {
                const float gzw = (dz == 1) ? 2.f : 1.f;
#pragma unroll
                for (int dy = 0; dy < 3; ++dy) {
                    const float gyw = (dy == 1) ? 2.f : 1.f;
                    const int off = cbase + dz * SZp + dy * SYp;
                    f32x2 a0, a1, a2;
                    a0.x = bA[off];     a0.y = bB[off];
                    a1.x = bA[off + 1]; a1.y = bB[off + 1];
                    a2.x = bA[off + 2]; a2.y = bB[off + 2];
                    const f32x2 two = {2.f, 2.f};
                    const f32x2 rs = a0 + two * a1 + a2; // v_pk contract
                    const f32x2 gy2 = {gyw, gyw};
                    const f32x2 gz2 = {gzw, gzw};
                    const f32x2 gw2 = {gzw * gyw, gzw * gyw};
                    if (dz == 0) P0 = pk_fma(gy2, rs, P0);
                    if (dz == 2) P2 = pk_fma(gy2, rs, P2);
                    if (dy == 0) U0 = pk_fma(gz2, rs, U0);
                    if (dy == 2) U2 = pk_fma(gz2, rs, U2);
                    V0 = pk_fma(gw2, a0, V0);
                    V2 = pk_fma(gw2, a2, V2);
                    if (dz == 1 && dy == 1) ctr2 = a1;
                    if (cg == 2) mx2 = pk_max(mx2, pk_max(pk_max(a0, a1), a2));
                }
            }
            if (cg == 2) amax = mx2.y; // alpha = channel 3 = .y of pair (2,3)

            const f32x2 sc = {0.0625f, 0.0625f};
            const f32x2 f1 = (P0 - P2) * sc;
            const f32x2 f2 = (U0 - U2) * sc;
            const f32x2 f3 = (V0 - V2) * sc;

            const int j = g * 4 + p; // == cg >> 1
            h2 v;
            v.x = (_Float16)ctr2.x; v.y = (_Float16)ctr2.y; pp[j]      = v;
            v.x = (_Float16)f1.x;   v.y = (_Float16)f1.y;   pp[8 + j]  = v;
            v.x = (_Float16)f2.x;   v.y = (_Float16)f2.y;   pp[16 + j] = v;
            v.x = (_Float16)f3.x;   v.y = (_Float16)f3.y;   pp[24 + j] = v;
        }
    }

    // All waves finished reading the buffers; X/H panels may overwrite.
    __syncthreads();

    const float pre = (amax > 0.1f) ? 1.f : 0.f; // own voxel

    // =================== MFMA MLP (wave-private) ===================
    const int lane = tid & 63;
    const int w    = tid >> 6;       // wave = z-slice
    const int l15  = lane & 15;
    const int lg   = lane >> 4;      // lane group 0..3
    char* xw = smem + w * XWAVE;

    // --- write X-panel: row v = lane, 64 f16, XOR-swizzled 16B slots ---
#pragma unroll
    for (int q = 0; q < 8; ++q) {
        uint4 t;
        t.x = __builtin_bit_cast(unsigned, pp[4 * q]);
        t.y = __builtin_bit_cast(unsigned, pp[4 * q + 1]);
        t.z = __builtin_bit_cast(unsigned, pp[4 * q + 2]);
        t.w = __builtin_bit_cast(unsigned, pp[4 * q + 3]);
        *(uint4*)(xw + lane * XROW + ((q * 16) ^ ((lane & 7) << 4))) = t;
    }

    // --- load B1 fragments (X^T): B[k][v], lane: k=lg*8+j, v=nt*16+l15 ---
    f16x8 bfr[8]; // [kt*4 + nt]
#pragma unroll
    for (int kt = 0; kt < 2; ++kt)
#pragma unroll
        for (int nt = 0; nt < 4; ++nt) {
            const int v = nt * 16 + l15;
            bfr[kt * 4 + nt] = *(const f16x8*)(
                xw + v * XROW + ((kt * 64 + lg * 16) ^ ((v & 7) << 4)));
        }

    // --- park the identity features (this thread's f16 s0) in the dead
    //     zone (6144..8192; issued after the bfr reads, per-wave in-order).
    //     pp[0..7] are then DEAD through the GEMM -> ~16 regs freed net.
    {
        uint4 ia, ib;
        ia.x = __builtin_bit_cast(unsigned, pp[0]);
        ia.y = __builtin_bit_cast(unsigned, pp[1]);
        ia.z = __builtin_bit_cast(unsigned, pp[2]);
        ia.w = __builtin_bit_cast(unsigned, pp[3]);
        ib.x = __builtin_bit_cast(unsigned, pp[4]);
        ib.y = __builtin_bit_cast(unsigned, pp[5]);
        ib.z = __builtin_bit_cast(unsigned, pp[6]);
        ib.w = __builtin_bit_cast(unsigned, pp[7]);
        *(uint4*)(xw + PARK0 + lane * 16) = ia;
        *(uint4*)(xw + PARK1 + lane * 16) = ib;
    }

    const f16x8* a1 = ((const f16x8*)a1p) + lane;
    const f16x8* a2 = ((const f16x8*)a2p) + lane;

    f32x4 acc2[4];
#pragma unroll
    for (int nt = 0; nt < 4; ++nt) acc2[nt] = (f32x4){0.f, 0.f, 0.f, 0.f};

    // --- interleaved GEMM1/GEMM2 per 32-row hidden block ---
#pragma unroll 1
    for (int kt2 = 0; kt2 < 3; ++kt2) {
#pragma unroll
        for (int mtsub = 0; mtsub < 2; ++mtsub) {
            const int mt = kt2 * 2 + mtsub;
            const f16x8 a_0 = a1[(mt * 2 + 0) * 64];
            const f16x8 a_1 = a1[(mt * 2 + 1) * 64];
            const f32x4 bias = *(const f32x4*)(b1 + mt * 16 + lg * 4);
#pragma unroll
            for (int nt = 0; nt < 4; ++nt) {
                f32x4 acc = (f32x4){0.f, 0.f, 0.f, 0.f};
                acc = mfma16(a_0, bfr[nt],     acc);
                acc = mfma16(a_1, bfr[4 + nt], acc);
                f16x4 hv;
                hv[0] = (_Float16)fmaxf(acc[0] + bias[0], 0.f);
                hv[1] = (_Float16)fmaxf(acc[1] + bias[1], 0.f);
                hv[2] = (_Float16)fmaxf(acc[2] + bias[2], 0.f);
                hv[3] = (_Float16)fmaxf(acc[3] + bias[3], 0.f);
                *(f16x4*)(xw + (nt * 16 + l15) * HROW + mtsub * 32 + lg * 8) = hv;
            }
        }
        const f16x8 a2f = a2[kt2 * 64];
#pragma unroll
        for (int nt = 0; nt < 4; ++nt) {
            const f16x8 b2 = *(const f16x8*)(xw + (nt * 16 + l15) * HROW + lg * 16);
            acc2[nt] = mfma16(a2f, b2, acc2[nt]);
        }
    }

    // --- delta transpose through the (now dead) H panel: row = voxel ---
#pragma unroll
    for (int nt = 0; nt < 4; ++nt) {
        *(f32x4*)(xw + (nt * 16 + l15) * HROW + lg * 16) = acc2[nt];
    }

    // --- epilogue: own voxel, all 16 channels; s0 = parked identity (f16,
    //     validated R17/R18) ---
    const float m = (ru < 0.5f) ? 1.f : 0.f;
    const uint4 ia = *(const uint4*)(xw + PARK0 + lane * 16);
    const uint4 ib = *(const uint4*)(xw + PARK1 + lane * 16);
    float s0v[16];
    {
        const unsigned wds[8] = {ia.x, ia.y, ia.z, ia.w, ib.x, ib.y, ib.z, ib.w};
#pragma unroll
        for (int j = 0; j < 8; ++j) {
            const h2 p = __builtin_bit_cast(h2, wds[j]);
            s0v[2 * j]     = (float)p.x;
            s0v[2 * j + 1] = (float)p.y;
        }
    }
    float* ob = out + (size_t)n * C * G3;
    float* ac = acopy + (size_t)n * G3;
#pragma unroll
    for (int q = 0; q < 4; ++q) {
        const f32x4 dv = *(const f32x4*)(xw + lane * HROW + q * 16);
#pragma unroll
        for (int r = 0; r < 4; ++r) {
            const int c = q * 4 + r;
            const float nv = fmaf(dv[r], m, s0v[c]);
            if (c == 3) ac[vofs] = nv; // UNMASKED new alpha
            ob[(size_t)c * G3 + vofs] = nv * pre;
        }
    }
}

// ---------------------------------------------------------------------------
// Pass 2 (fused): post-alive pooling on the unmasked new alpha (acopy) ->
// zero out dead voxels only. Alive voxels (overwhelming majority) touch no
// out traffic: multiplying by 1 is a no-op. Bit-exact vs out *= mask.
// ---------------------------------------------------------------------------
__global__ __launch_bounds__(256)
void nca_post(const float* __restrict__ acopy, float* __restrict__ out)
{
    const int idx = blockIdx.x * 256 + threadIdx.x; // over NBATCH*G3
    const int n = idx >> 18;
    const int v = idx & (G3 - 1);
    const int x = v & 63, y = (v >> 6) & 63, z = v >> 12;
    const float* ab = acopy + (size_t)n * G3;
    float mx = -3.0e38f;
#pragma unroll
    for (int dz = -1; dz <= 1; ++dz) {
        const int zz = min(max(z + dz, 0), G - 1);
#pragma unroll
        for (int dy = -1; dy <= 1; ++dy) {
            const int yy = min(max(y + dy, 0), G - 1);
            const int xm = max(x - 1, 0), xp = min(x + 1, G - 1);
            const float* row = ab + (size_t)zz * (G * G) + (size_t)yy * G;
            mx = fmaxf(mx, fmaxf(fmaxf(row[xm], row[x]), row[xp]));
        }
    }
    if (mx > 0.1f) return; // alive: out already holds new_state * pre
    float* ob = out + (size_t)n * C * G3 + v;
#pragma unroll
    for (int c = 0; c < C; ++c) ob[(size_t)c * G3] = 0.f;
}

extern "C" void kernel_launch(void* const* d_in, const int* in_sizes, int n_in,
                              void* d_out, int out_size, void* d_ws, size_t ws_size,
                              hipStream_t stream)
{
    const float* state  = (const float*)d_in[0];
    const float* rand_u = (const float*)d_in[1];
    const float* w1     = (const float*)d_in[2];
    const float* b1     = (const float*)d_in[3];
    const float* w2     = (const float*)d_in[4];
    float* out  = (float*)d_out;

    // Workspace: [0,12KB) a1p, [12KB,15KB) a2p, [16KB, 16KB+4MiB) acopy.
    _Float16* a1p  = (_Float16*)d_ws;
    _Float16* a2p  = (_Float16*)((char*)d_ws + 12 * 1024);
    float*    acop = (float*)((char*)d_ws + 16 * 1024);

    nca_packw <<<24, 256, 0, stream>>>(w1, w2, a1p, a2p);
    nca_update<<<NBATCH * 8 * 8 * 16, 256, 0, stream>>>(state, rand_u, a1p, b1, a2p, out, acop);
    nca_post  <<<(NBATCH * G3) / 256, 256, 0, stream>>>(acop, out);
}

// Round 23
// 112.613 us; speedup vs baseline: 1.2174x; 1.0490x over previous
//
#include <hip/hip_runtime.h>

constexpr int G = 64;
constexpr int C = 16;
constexpr int NBATCH = 4;
constexpr int HID = 96;
constexpr int G3 = G * G * G; // 262144 = 2^18

typedef _Float16 h2    __attribute__((ext_vector_type(2)));
typedef _Float16 f16x4 __attribute__((ext_vector_type(4)));
typedef _Float16 f16x8 __attribute__((ext_vector_type(8)));
typedef float    f32x4 __attribute__((ext_vector_type(4)));

__device__ __forceinline__ f32x4 mfma16(f16x8 a, f16x8 b, f32x4 c) {
    return __builtin_amdgcn_mfma_f32_16x16x32_f16(a, b, c, 0, 0, 0);
}

#if __has_builtin(__builtin_amdgcn_global_load_lds)
#define HAS_GLL 1
__device__ __forceinline__ void gload_lds(const float* g, float* l) {
    __builtin_amdgcn_global_load_lds(
        (const __attribute__((address_space(1))) void*)g,
        (__attribute__((address_space(3))) void*)l, 4, 0, 0);
}
#else
#define HAS_GLL 0
#endif

// ---------------------------------------------------------------------------
// Pass 0: pack W1 (96x64) and W2 (16x96) into MFMA A-fragment order (f16).
// A-frag for mfma_f32_16x16x32_f16: lane l holds A[row = l%16][k = (l/16)*8+j],
// j=0..7 (16B contiguous per lane). (Layout verified by R11: absmax 0.03125.)
// ---------------------------------------------------------------------------
__global__ __launch_bounds__(256)
void nca_packw(const float* __restrict__ w1, const float* __restrict__ w2,
               _Float16* __restrict__ a1p, _Float16* __restrict__ a2p)
{
    const int i = blockIdx.x * 256 + threadIdx.x; // 0..6143
    {
        const int j = i & 7, lane = (i >> 3) & 63, f = i >> 9; // f = mt*2+kt
        const int mt = f >> 1, kt = f & 1;
        const int y = mt * 16 + (lane & 15);
        const int x = kt * 32 + ((lane >> 4) << 3) + j;
        a1p[i] = (_Float16)w1[y * 64 + x];
    }
    if (i < 3 * 512) {
        const int j = i & 7, lane = (i >> 3) & 63, kt2 = i >> 9;
        const int c = lane & 15;
        const int y = kt2 * 32 + ((lane >> 4) << 3) + j;
        a2p[i] = (_Float16)w2[c * HID + y];
    }
}

// ---------------------------------------------------------------------------
// Pass 1: perception + MFMA MLP + pre-alive fold-in.
//
// R23 = R16 verbatim — the session's proven best (110.2 us total, update
// 105.5 us, 84 VGPR, ZERO spill, FETCH 180 MB = structural ideal).
// Rationale: R17-R22 established by five independent spill events that the
// stencil+GEMM+voxel-major-epilogue live set is ~85-95 registers; every
// attempt to drop below (64-tier: R17/R18/R19) or add work per register
// (pk-f32: R21/R22) spilled, and spill round-trips cost more than the
// targeted optimization saved. R20's swizzle/padding variant is
// noise-equivalent (111.7). This configuration is the measured optimum of
// the design space explored: async gload_lds double-buffered staging
// (zero-VGPR, one HBM round hidden), MFMA MLP via wave-private X/H panels,
// voxel-major epilogue (ctrf s0, own rand, lazy post-mask).
// Structure is latency-composition-bound at ~30% on all pipes; HBM floor
// ~43 us, VALU floor ~45 us @ 12 waves/CU.
// ---------------------------------------------------------------------------
constexpr int HALO_N = 600;       // 10*10*6, linear per channel
constexpr int BUF_F  = 8 * HALO_N;// 4800 floats per group buffer
constexpr int XROW = 144;         // X-panel row stride (bytes)
constexpr int HROW = 80;          // H / delta-transpose row stride (bytes)
constexpr int XWAVE = 64 * XROW;  // 9216 B per wave

__global__ __launch_bounds__(256, 3)
void nca_update(const float* __restrict__ state, const float* __restrict__ rand_u,
                const _Float16* __restrict__ a1p, const float* __restrict__ b1,
                const _Float16* __restrict__ a2p,
                float* __restrict__ out, float* __restrict__ acopy)
{
    // 2 x 4800 floats (stencil) = 38400 B; GEMM panels (4 x 9216 = 36864 B)
    // alias the same region after the post-stencil barrier.
    __shared__ __align__(16) char smem[2 * BUF_F * 4];
    float* buf0 = (float*)smem;
    float* buf1 = buf0 + BUF_F;

    const int tid = threadIdx.x;
    const int bid = blockIdx.x;
    const int bx = bid & 7, by = (bid >> 3) & 7, bz = (bid >> 6) & 15, n = bid >> 10;
    const int x0 = bx * 8, y0 = by * 8, z0 = bz * 4;
    const float* sb = state + (size_t)n * C * G3;

    // --- halo source offsets, linear j-order (identical every channel) ---
    int vo0, vo1, vo2;
    {
        const int j = tid;
        const int lx = j % 10, t = j / 10, ly = t % 10, lz = t / 10;
        vo0 = min(max(z0 + lz - 1, 0), G - 1) * (G * G)
            + min(max(y0 + ly - 1, 0), G - 1) * G
            + min(max(x0 + lx - 1, 0), G - 1);
    }
    {
        const int j = tid + 256;
        const int lx = j % 10, t = j / 10, ly = t % 10, lz = t / 10;
        vo1 = min(max(z0 + lz - 1, 0), G - 1) * (G * G)
            + min(max(y0 + ly - 1, 0), G - 1) * G
            + min(max(x0 + lx - 1, 0), G - 1);
    }
    const bool act2 = (tid + 512 < HALO_N);
    {
        const int j = min(tid + 512, HALO_N - 1);
        const int lx = j % 10, t = j / 10, ly = t % 10, lz = t / 10;
        vo2 = min(max(z0 + lz - 1, 0), G - 1) * (G * G)
            + min(max(y0 + ly - 1, 0), G - 1) * G
            + min(max(x0 + lx - 1, 0), G - 1);
    }
    const int wbase = tid & ~63; // wave-uniform LDS slot base

    // Own voxel (== lane's voxel of wave's z-slice).
    const int lxl = (tid & 7) + 1, lyl = ((tid >> 3) & 7) + 1, lzl = (tid >> 6) + 1;
    const int cbase = (lzl - 1) * 100 + (lyl - 1) * 10 + (lxl - 1);
    const size_t vofs = (size_t)(z0 + lzl - 1) * (G * G)
                      + (size_t)(y0 + lyl - 1) * G + (x0 + lxl - 1);
    const float ru = rand_u[(size_t)n * G3 + vofs]; // own rand, issued early

#if HAS_GLL
    // --- issue group 0 (ch 0-7) -> buf0, async, zero VGPR ---
#pragma unroll
    for (int c = 0; c < 8; ++c) {
        const float* gc = sb + (size_t)c * G3;
        gload_lds(gc + vo0, buf0 + c * HALO_N + wbase);
        gload_lds(gc + vo1, buf0 + c * HALO_N + 256 + wbase);
        if (act2) gload_lds(gc + vo2, buf0 + c * HALO_N + 512 + wbase);
    }
    __syncthreads(); // drains vmcnt -> buf0 complete

    // --- issue group 1 (ch 8-15) -> buf1; latency hides under stencil g0 ---
#pragma unroll
    for (int c = 0; c < 8; ++c) {
        const float* gc = sb + (size_t)(8 + c) * G3;
        gload_lds(gc + vo0, buf1 + c * HALO_N + wbase);
        gload_lds(gc + vo1, buf1 + c * HALO_N + 256 + wbase);
        if (act2) gload_lds(gc + vo2, buf1 + c * HALO_N + 512 + wbase);
    }
#else
    // Fallback: synchronous staging (correct, no overlap).
#pragma unroll
    for (int c = 0; c < 8; ++c) {
        const float* gc = sb + (size_t)c * G3;
        buf0[c * HALO_N + tid] = gc[vo0];
        buf0[c * HALO_N + 256 + tid] = gc[vo1];
        if (act2) buf0[c * HALO_N + 512 + tid] = gc[vo2];
    }
    __syncthreads();
#pragma unroll
    for (int c = 0; c < 8; ++c) {
        const float* gc = sb + (size_t)(8 + c) * G3;
        buf1[c * HALO_N + tid] = gc[vo0];
        buf1[c * HALO_N + 256 + tid] = gc[vo1];
        if (act2) buf1[c * HALO_N + 512 + tid] = gc[vo2];
    }
#endif

    // Packed perception features + exact fp32 centers.
    h2 pp[32];
    float ctrf[C]; // own-voxel centers: exact s0 passthrough, no re-read
    float pf0 = 0.f, pf1 = 0.f, pf2 = 0.f, pf3 = 0.f; // even-channel carry
    float amax = -3.0e38f;

#pragma unroll
    for (int g = 0; g < 2; ++g) {
        const float* bb = g ? buf1 : buf0;
        if (g) __syncthreads(); // drains buf1's loads (issued pre-stencil-g0)

#pragma unroll
        for (int c = 0; c < 8; ++c) {
            const int cg = g * 8 + c;
            const float* buf = bb + c * HALO_N;
            float P0 = 0.f, P2 = 0.f, U0 = 0.f, U2 = 0.f, V0 = 0.f, V2 = 0.f;
            float ctr = 0.f, mx = -3.0e38f;
#pragma unroll
            for (int dz = 0; dz < 3; ++dz) {
                const float gzw = (dz == 1) ? 2.f : 1.f;
#pragma unroll
                for (int dy = 0; dy < 3; ++dy) {
                    const float gyw = (dy == 1) ? 2.f : 1.f;
                    const float* r = buf + cbase + dz * 100 + dy * 10;
                    const float a0 = r[0], a1 = r[1], a2 = r[2];
                    const float rs = a0 + 2.f * a1 + a2;
                    if (dz == 0) P0 += gyw * rs;
                    if (dz == 2) P2 += gyw * rs;
                    if (dy == 0) U0 += gzw * rs;
                    if (dy == 2) U2 += gzw * rs;
                    V0 += gzw * gyw * a0;
                    V2 += gzw * gyw * a2;
                    if (dz == 1 && dy == 1) ctr = a1;
                    if (cg == 3) mx = fmaxf(mx, fmaxf(fmaxf(a0, a1), a2));
                }
            }
            if (cg == 3) amax = mx;
            ctrf[cg] = ctr;

            const float f0 = ctr;
            const float f1 = (P0 - P2) * 0.0625f;
            const float f2 = (U0 - U2) * 0.0625f;
            const float f3 = (V0 - V2) * 0.0625f;

            if (cg & 1) {
                const int j = cg >> 1;
                h2 v;
                v.x = (_Float16)pf0; v.y = (_Float16)f0; pp[j]      = v;
                v.x = (_Float16)pf1; v.y = (_Float16)f1; pp[8 + j]  = v;
                v.x = (_Float16)pf2; v.y = (_Float16)f2; pp[16 + j] = v;
                v.x = (_Float16)pf3; v.y = (_Float16)f3; pp[24 + j] = v;
            } else {
                pf0 = f0; pf1 = f1; pf2 = f2; pf3 = f3;
            }
        }
    }

    // All waves finished reading the buffers; X/H panels may overwrite.
    __syncthreads();

    const float pre = (amax > 0.1f) ? 1.f : 0.f; // own voxel

    // =================== MFMA MLP (wave-private) ===================
    const int lane = tid & 63;
    const int w    = tid >> 6;       // wave = z-slice
    const int l15  = lane & 15;
    const int lg   = lane >> 4;      // lane group 0..3
    char* xw = smem + w * XWAVE;

    // --- write X-panel: row v = lane (this thread's voxel), 64 f16 ---
#pragma unroll
    for (int q = 0; q < 8; ++q) {
        uint4 t;
        t.x = __builtin_bit_cast(unsigned, pp[4 * q]);
        t.y = __builtin_bit_cast(unsigned, pp[4 * q + 1]);
        t.z = __builtin_bit_cast(unsigned, pp[4 * q + 2]);
        t.w = __builtin_bit_cast(unsigned, pp[4 * q + 3]);
        *(uint4*)(xw + lane * XROW + q * 16) = t;
    }

    // --- load B1 fragments (X^T): B[k][v], lane: k=lg*8+j, v=nt*16+l15 ---
    f16x8 bfr[8]; // [kt*4 + nt]
#pragma unroll
    for (int kt = 0; kt < 2; ++kt)
#pragma unroll
        for (int nt = 0; nt < 4; ++nt)
            bfr[kt * 4 + nt] = *(const f16x8*)(xw + (nt * 16 + l15) * XROW + kt * 64 + lg * 16);

    const f16x8* a1 = ((const f16x8*)a1p) + lane;
    const f16x8* a2 = ((const f16x8*)a2p) + lane;

    f32x4 acc2[4];
#pragma unroll
    for (int nt = 0; nt < 4; ++nt) acc2[nt] = (f32x4){0.f, 0.f, 0.f, 0.f};

    // --- interleaved GEMM1/GEMM2 per 32-row hidden block ---
#pragma unroll 1
    for (int kt2 = 0; kt2 < 3; ++kt2) {
#pragma unroll
        for (int mtsub = 0; mtsub < 2; ++mtsub) {
            const int mt = kt2 * 2 + mtsub;
            const f16x8 a_0 = a1[(mt * 2 + 0) * 64];
            const f16x8 a_1 = a1[(mt * 2 + 1) * 64];
            const f32x4 bias = *(const f32x4*)(b1 + mt * 16 + lg * 4);
#pragma unroll
            for (int nt = 0; nt < 4; ++nt) {
                f32x4 acc = (f32x4){0.f, 0.f, 0.f, 0.f};
                acc = mfma16(a_0, bfr[nt],     acc);
                acc = mfma16(a_1, bfr[4 + nt], acc);
                f16x4 hv;
                hv[0] = (_Float16)fmaxf(acc[0] + bias[0], 0.f);
                hv[1] = (_Float16)fmaxf(acc[1] + bias[1], 0.f);
                hv[2] = (_Float16)fmaxf(acc[2] + bias[2], 0.f);
                hv[3] = (_Float16)fmaxf(acc[3] + bias[3], 0.f);
                *(f16x4*)(xw + (nt * 16 + l15) * HROW + mtsub * 32 + lg * 8) = hv;
            }
        }
        const f16x8 a2f = a2[kt2 * 64];
#pragma unroll
        for (int nt = 0; nt < 4; ++nt) {
            const f16x8 b2 = *(const f16x8*)(xw + (nt * 16 + l15) * HROW + lg * 16);
            acc2[nt] = mfma16(a2f, b2, acc2[nt]);
        }
    }

    // --- delta transpose through the (now dead) H panel: row = voxel ---
#pragma unroll
    for (int nt = 0; nt < 4; ++nt) {
        *(f32x4*)(xw + (nt * 16 + l15) * HROW + lg * 16) = acc2[nt];
    }

    // --- epilogue: own voxel, all 16 channels; s0 = ctrf (exact fp32) ---
    const float m = (ru < 0.5f) ? 1.f : 0.f;
    float* ob = out + (size_t)n * C * G3;
    float* ac = acopy + (size_t)n * G3;
#pragma unroll
    for (int q = 0; q < 4; ++q) {
        const f32x4 dv = *(const f32x4*)(xw + lane * HROW + q * 16);
#pragma unroll
        for (int r = 0; r < 4; ++r) {
            const int c = q * 4 + r;
            const float nv = fmaf(dv[r], m, ctrf[c]);
            if (c == 3) ac[vofs] = nv; // UNMASKED new alpha
            ob[(size_t)c * G3 + vofs] = nv * pre;
        }
    }
}

// ---------------------------------------------------------------------------
// Pass 2 (fused): post-alive pooling on the unmasked new alpha (acopy) ->
// zero out dead voxels only. Alive voxels (overwhelming majority) touch no
// out traffic: multiplying by 1 is a no-op. Bit-exact vs out *= mask.
// ---------------------------------------------------------------------------
__global__ __launch_bounds__(256)
void nca_post(const float* __restrict__ acopy, float* __restrict__ out)
{
    const int idx = blockIdx.x * 256 + threadIdx.x; // over NBATCH*G3
    const int n = idx >> 18;
    const int v = idx & (G3 - 1);
    const int x = v & 63, y = (v >> 6) & 63, z = v >> 12;
    const float* ab = acopy + (size_t)n * G3;
    float mx = -3.0e38f;
#pragma unroll
    for (int dz = -1; dz <= 1; ++dz) {
        const int zz = min(max(z + dz, 0), G - 1);
#pragma unroll
        for (int dy = -1; dy <= 1; ++dy) {
            const int yy = min(max(y + dy, 0), G - 1);
            const int xm = max(x - 1, 0), xp = min(x + 1, G - 1);
            const float* row = ab + (size_t)zz * (G * G) + (size_t)yy * G;
            mx = fmaxf(mx, fmaxf(fmaxf(row[xm], row[x]), row[xp]));
        }
    }
    if (mx > 0.1f) return; // alive: out already holds new_state * pre
    float* ob = out + (size_t)n * C * G3 + v;
#pragma unroll
    for (int c = 0; c < C; ++c) ob[(size_t)c * G3] = 0.f;
}

extern "C" void kernel_launch(void* const* d_in, const int* in_sizes, int n_in,
                              void* d_out, int out_size, void* d_ws, size_t ws_size,
                              hipStream_t stream)
{
    const float* state  = (const float*)d_in[0];
    const float* rand_u = (const float*)d_in[1];
    const float* w1     = (const float*)d_in[2];
    const float* b1     = (const float*)d_in[3];
    const float* w2     = (const float*)d_in[4];
    float* out  = (float*)d_out;

    // Workspace: [0,12KB) a1p, [12KB,15KB) a2p, [16KB, 16KB+4MiB) acopy.
    _Float16* a1p  = (_Float16*)d_ws;
    _Float16* a2p  = (_Float16*)((char*)d_ws + 12 * 1024);
    float*    acop = (float*)((char*)d_ws + 16 * 1024);

    nca_packw <<<24, 256, 0, stream>>>(w1, w2, a1p, a2p);
    nca_update<<<NBATCH * 8 * 8 * 16, 256, 0, stream>>>(state, rand_u, a1p, b1, a2p, out, acop);
    nca_post  <<<(NBATCH * G3) / 256, 256, 0, stream>>>(acop, out);
}